// Round 2
// baseline (11421.225 us; speedup 1.0000x reference)
//
#include <hip/hip_runtime.h>

typedef unsigned int u32;
typedef unsigned short u16;
typedef unsigned long long u64;
typedef float f32x4 __attribute__((ext_vector_type(4)));
typedef _Float16 f16x8 __attribute__((ext_vector_type(8)));

#define S_LEN 1024
#define NG 8      // groups (one per XCD, heuristically)
#define NM 32     // member blocks per group
#define GBAT 16   // batches per group

__device__ __forceinline__ u16 f2h_bits(float f) {
  _Float16 h = (_Float16)f;
  return __builtin_bit_cast(u16, h);
}
__device__ __forceinline__ float h2f_bits(u16 b) {
  return (float)__builtin_bit_cast(_Float16, b);
}

// Pre-arrange W into MFMA fragment-major order, fp16.
// Per member m: frag[q(gate 0..3)][kc(0..15)][lane(0..63)] = uint4 (8 f16).
// Element (lane,e): k = kc*32 + (lane>>4)*8 + e ; gcol = q*512 + m*16 + (lane&15).
// Wi frags at wf4[0 .. 32*4096), Wh frags at +131072 uint4.
__global__ __launch_bounds__(256) void prep_frags(const float* __restrict__ Wi,
                                                  const float* __restrict__ Wh,
                                                  uint4* __restrict__ wf4) {
  const int blk = blockIdx.x;               // 0..63
  const int m = blk & 31;
  const float* __restrict__ W = (blk & 32) ? Wh : Wi;
  uint4* __restrict__ dst = wf4 + ((blk & 32) ? 131072 : 0) + m * 4096;
  for (int fi = threadIdx.x; fi < 4096; fi += 256) {
    const int lane = fi & 63;
    const int kc = (fi >> 6) & 15;
    const int q = fi >> 10;
    const int gq = lane >> 4, c = lane & 15;
    const int kb = kc * 32 + gq * 8;
    const int gcol = q * 512 + m * 16 + c;
    u32 wds[4];
#pragma unroll
    for (int pp = 0; pp < 4; ++pp) {
      u16 e0 = f2h_bits(W[(size_t)(kb + 2 * pp) * 2048 + gcol]);
      u16 e1 = f2h_bits(W[(size_t)(kb + 2 * pp + 1) * 2048 + gcol]);
      wds[pp] = (u32)e0 | ((u32)e1 << 16);
    }
    uint4 v; v.x = wds[0]; v.y = wds[1]; v.z = wds[2]; v.w = wds[3];
    dst[fi] = v;    // fi == (q*16+kc)*64+lane
  }
}

// Persistent LSTM kernel. Group g = bid&7 owns batches [g*16,g*16+16);
// member m = bid>>3 owns h-indices [m*16,m*16+16) (gate cols {hidx, +512, +1024, +1536}).
// hbuf[2][128][512] u32: packed (f16_hi<<16 | f16_lo) of h, exchanged via agent-scope atomics.
__global__ __launch_bounds__(256) void lstm_main(
    const float* __restrict__ x,
    const uint4* __restrict__ wif4,
    u32* __restrict__ hbuf,
    u32* __restrict__ bar,              // NG counters, 128B apart
    const float* __restrict__ bvec,
    const float* __restrict__ Wd,
    const float* __restrict__ bd,
    float* __restrict__ out) {
  // sA: A fragments, uint4-indexed:
  //   [0,1024)      x  hi  (kc 0..15)
  //   [1024,2048)   h  hi  (kc 16..31)
  //   [2048,3072)   x  lo
  //   [3072,4096)   h  lo
  // sB: Wh fragments [q][kc 0..15][lane][8 f16]           (64KB)
  __shared__ __align__(16) u16 sA[2 * 16384];
  __shared__ __align__(16) u16 sB[32768];
  float* __restrict__ pred = reinterpret_cast<float*>(sA);  // aliases x-hi region after MFMA reads

  const int tid = threadIdx.x;
  const int lane = tid & 63;
  const int wv = tid >> 6;
  const int g = blockIdx.x & 7;
  const int m = blockIdx.x >> 3;

  const uint4* __restrict__ wifm = wif4 + m * 4096;
  const uint4* __restrict__ whfm = wif4 + 131072 + m * 4096;

  {  // Wh frags -> LDS (once)
    uint4* sB4 = reinterpret_cast<uint4*>(sB);
    for (int i = tid; i < 4096; i += 256) sB4[i] = whfm[i];
  }

  const int bt = tid >> 4;          // batch within group
  const int hi_ = tid & 15;         // h-index within member slice
  const int gb = g * GBAT + bt;
  const int hidx = m * 16 + hi_;

  const float bi = bvec[hidx];
  const float bf_ = bvec[512 + hidx];
  const float bg = bvec[1024 + hidx];
  const float bo = bvec[1536 + hidx];
  float c_reg = 0.f;

  u32* const barp = bar + g * 32;

  // init h(0) = 0 (own slice), then arrive
  __hip_atomic_store(&hbuf[(u32)gb * 512u + (u32)hidx], 0u, __ATOMIC_RELAXED,
                     __HIP_MEMORY_SCOPE_AGENT);
  __syncthreads();
  if (tid == 0)
    __hip_atomic_fetch_add(barp, 1u, __ATOMIC_RELEASE, __HIP_MEMORY_SCOPE_AGENT);

  for (int t = 0; t < S_LEN; ++t) {
    const int p = t & 1;

    // ---- stage x(t) -> sA x-planes; independent of h: hides under barrier
#pragma unroll
    for (int j = 0; j < 4; ++j) {
      const int cidx = (tid << 2) | j;
      const int btc = cidx >> 6;
      const int k0 = (cidx & 63) << 3;
      const float4* src = reinterpret_cast<const float4*>(
          x + (size_t)(g * GBAT + btc) * (S_LEN * 512) + (size_t)t * 512 + k0);
      float4 va = src[0], vb2 = src[1];
      float vv[8] = {va.x, va.y, va.z, va.w, vb2.x, vb2.y, vb2.z, vb2.w};
      u32 wh[4], wl[4];
#pragma unroll
      for (int pp = 0; pp < 4; ++pp) {
        float v0 = vv[2 * pp], v1 = vv[2 * pp + 1];
        u16 h0b = f2h_bits(v0); u16 h1b = f2h_bits(v1);
        u16 l0b = f2h_bits(v0 - h2f_bits(h0b));
        u16 l1b = f2h_bits(v1 - h2f_bits(h1b));
        wh[pp] = (u32)h0b | ((u32)h1b << 16);
        wl[pp] = (u32)l0b | ((u32)l1b << 16);
      }
      const int kc = k0 >> 5;
      const int ln = (((k0 >> 3) & 3) << 4) | btc;
      uint4 vh; vh.x = wh[0]; vh.y = wh[1]; vh.z = wh[2]; vh.w = wh[3];
      uint4 vl; vl.x = wl[0]; vl.y = wl[1]; vl.z = wl[2]; vl.w = wl[3];
      *reinterpret_cast<uint4*>(&sA[(kc * 64 + ln) * 8]) = vh;
      *reinterpret_cast<uint4*>(&sA[16384 + (kc * 64 + ln) * 8]) = vl;
    }

    // ---- wait for h(t) from all group members
    if (tid == 0) {
      const u32 target = (u32)NM * (u32)(t + 1);
      while (__hip_atomic_load(barp, __ATOMIC_RELAXED, __HIP_MEMORY_SCOPE_AGENT) < target)
        __builtin_amdgcn_s_sleep(1);
    }
    __syncthreads();

    // ---- stage h(t) -> sA h-planes via LLC-coherent atomic loads
    {
      const u32* hb = hbuf + (u32)p * 65536u;
#pragma unroll
      for (int j = 0; j < 4; ++j) {
        const int cidx = (tid << 2) | j;
        const int btc = cidx >> 6;
        const int h0 = (cidx & 63) << 3;
        const u64* src = reinterpret_cast<const u64*>(hb + ((u32)(g * GBAT + btc) << 9) + (u32)h0);
        u32 pk[8];
#pragma unroll
        for (int ee = 0; ee < 4; ++ee) {
          u64 v = __hip_atomic_load(src + ee, __ATOMIC_RELAXED, __HIP_MEMORY_SCOPE_AGENT);
          pk[2 * ee] = (u32)v; pk[2 * ee + 1] = (u32)(v >> 32);
        }
        uint4 vh, vl;
        vh.x = (pk[0] >> 16) | (pk[1] & 0xFFFF0000u);
        vh.y = (pk[2] >> 16) | (pk[3] & 0xFFFF0000u);
        vh.z = (pk[4] >> 16) | (pk[5] & 0xFFFF0000u);
        vh.w = (pk[6] >> 16) | (pk[7] & 0xFFFF0000u);
        vl.x = (pk[0] & 0xFFFFu) | (pk[1] << 16);
        vl.y = (pk[2] & 0xFFFFu) | (pk[3] << 16);
        vl.z = (pk[4] & 0xFFFFu) | (pk[5] << 16);
        vl.w = (pk[6] & 0xFFFFu) | (pk[7] << 16);
        const int kc = 16 + (h0 >> 5);
        const int ln = (((h0 >> 3) & 3) << 4) | btc;
        *reinterpret_cast<uint4*>(&sA[(kc * 64 + ln) * 8]) = vh;
        *reinterpret_cast<uint4*>(&sA[16384 + (kc * 64 + ln) * 8]) = vl;
      }
    }
    __syncthreads();

    // ---- MFMA: wave wv owns kc in [wv*8, wv*8+8); waves 0,1 use Wi frags (L2), 2,3 use Wh (LDS)
    f32x4 acc[4] = {{0, 0, 0, 0}, {0, 0, 0, 0}, {0, 0, 0, 0}, {0, 0, 0, 0}};
    {
      const uint4* sA4 = reinterpret_cast<const uint4*>(sA);
      if (wv < 2) {
#pragma unroll
        for (int kk = 0; kk < 8; ++kk) {
          const int kc = (wv << 3) | kk;
          f16x8 ah = __builtin_bit_cast(f16x8, sA4[kc * 64 + lane]);
          f16x8 al = __builtin_bit_cast(f16x8, sA4[2048 + kc * 64 + lane]);  // FIX: lo plane at uint4 2048
#pragma unroll
          for (int q = 0; q < 4; ++q) {
            f16x8 bb = __builtin_bit_cast(f16x8, wifm[(q * 16 + kc) * 64 + lane]);
            acc[q] = __builtin_amdgcn_mfma_f32_16x16x32_f16(ah, bb, acc[q], 0, 0, 0);
            acc[q] = __builtin_amdgcn_mfma_f32_16x16x32_f16(al, bb, acc[q], 0, 0, 0);
          }
        }
      } else {
        const uint4* sB4 = reinterpret_cast<const uint4*>(sB);
#pragma unroll
        for (int kk = 0; kk < 8; ++kk) {
          const int kc = (wv << 3) | kk;   // 16..31
          const int kcb = kc - 16;
          f16x8 ah = __builtin_bit_cast(f16x8, sA4[kc * 64 + lane]);
          f16x8 al = __builtin_bit_cast(f16x8, sA4[2048 + kc * 64 + lane]);  // FIX: lo plane at uint4 2048
#pragma unroll
          for (int q = 0; q < 4; ++q) {
            f16x8 bb = __builtin_bit_cast(f16x8, sB4[(q * 16 + kcb) * 64 + lane]);
            acc[q] = __builtin_amdgcn_mfma_f32_16x16x32_f16(ah, bb, acc[q], 0, 0, 0);
            acc[q] = __builtin_amdgcn_mfma_f32_16x16x32_f16(al, bb, acc[q], 0, 0, 0);
          }
        }
      }
    }
    __syncthreads();  // all sA reads done; safe to overwrite with pred

    // ---- write K-partial tiles (C/D layout: row=(l>>4)*4+r, col=l&15)
    {
      const int r0 = (lane >> 4) << 2;
      const int cc = lane & 15;
#pragma unroll
      for (int q = 0; q < 4; ++q)
#pragma unroll
        for (int r = 0; r < 4; ++r)
          pred[(wv * 4 + q) * 256 + (r0 + r) * 16 + cc] = acc[q][r];
    }
    __syncthreads();

    // ---- elementwise gate math; c in fp32 regs; publish h(t+1)
    {
      float gi = bi, gf = bf_, gg = bg, go = bo;
#pragma unroll
      for (int w2 = 0; w2 < 4; ++w2) {
        gi += pred[(w2 * 4 + 0) * 256 + tid];
        gf += pred[(w2 * 4 + 1) * 256 + tid];
        gg += pred[(w2 * 4 + 2) * 256 + tid];
        go += pred[(w2 * 4 + 3) * 256 + tid];
      }
      const float si = 1.f / (1.f + __expf(-gi));
      const float sf = 1.f / (1.f + __expf(-gf));
      const float so = 1.f / (1.f + __expf(-go));
      c_reg = sf * c_reg + si * tanhf(gg);
      const float hv = so * tanhf(c_reg);
      const u16 hh = f2h_bits(hv);
      const u16 hl = f2h_bits(hv - h2f_bits(hh));
      const u32 packed = ((u32)hh << 16) | (u32)hl;
      __hip_atomic_store(&hbuf[(u32)(1 - p) * 65536u + (u32)gb * 512u + (u32)hidx],
                         packed, __ATOMIC_RELAXED, __HIP_MEMORY_SCOPE_AGENT);
    }
    __syncthreads();
    if (tid == 0)
      __hip_atomic_fetch_add(barp, 1u, __ATOMIC_RELEASE, __HIP_MEMORY_SCOPE_AGENT);
  }

  // ---- Dense(1) on h(S): member 0 of each group handles its 16 batches
  if (m == 0) {
    if (tid == 0) {
      const u32 target = (u32)NM * (u32)(S_LEN + 1);
      while (__hip_atomic_load(barp, __ATOMIC_RELAXED, __HIP_MEMORY_SCOPE_AGENT) < target)
        __builtin_amdgcn_s_sleep(1);
    }
    __syncthreads();
    const int btf = tid >> 4;
    const int part = tid & 15;
    float acc = 0.f;
    const int h0b = part * 32;
#pragma unroll
    for (int j = 0; j < 16; ++j) {
      const int h0 = h0b + 2 * j;
      u64 v = __hip_atomic_load(
          reinterpret_cast<const u64*>(hbuf + ((u32)(g * GBAT + btf) << 9) + (u32)h0),
          __ATOMIC_RELAXED, __HIP_MEMORY_SCOPE_AGENT);
      const u32 w0 = (u32)v, w1 = (u32)(v >> 32);
      const float hv0 = h2f_bits((u16)(w0 >> 16)) + h2f_bits((u16)(w0 & 0xFFFFu));
      const float hv1 = h2f_bits((u16)(w1 >> 16)) + h2f_bits((u16)(w1 & 0xFFFFu));
      acc += hv0 * Wd[h0] + hv1 * Wd[h0 + 1];
    }
#pragma unroll
    for (int s = 1; s < 16; s <<= 1) acc += __shfl_xor(acc, s, 64);
    if (part == 0) out[g * GBAT + btf] = acc + bd[0];
  }
}

extern "C" void kernel_launch(void* const* d_in, const int* in_sizes, int n_in,
                              void* d_out, int out_size, void* d_ws, size_t ws_size,
                              hipStream_t stream) {
  const float* x = (const float*)d_in[0];
  const float* Wi = (const float*)d_in[1];
  const float* Wh = (const float*)d_in[2];
  const float* bv = (const float*)d_in[3];
  const float* Wd = (const float*)d_in[4];
  const float* bd = (const float*)d_in[5];
  float* out = (float*)d_out;

  // ws layout: [0,4KB) barrier counters | [4KB, 4KB+4MB) W frags | [+512KB) h ping-pong
  char* ws = (char*)d_ws;
  u32* bar = (u32*)ws;
  uint4* wif4 = (uint4*)(ws + 4096);
  u32* hbuf = (u32*)(ws + 4096 + (4u << 20));

  hipMemsetAsync(bar, 0, 4096, stream);
  hipLaunchKernelGGL(prep_frags, dim3(64), dim3(256), 0, stream, Wi, Wh, wif4);

  const float* kx = x;
  const uint4* kw = wif4;
  u32* kh = hbuf;
  u32* kb = bar;
  const float* kbv = bv;
  const float* kwd = Wd;
  const float* kbd = bd;
  float* ko = out;
  void* args[] = {&kx, &kw, &kh, &kb, &kbv, &kwd, &kbd, &ko};
  hipLaunchCooperativeKernel(reinterpret_cast<void*>(lstm_main), dim3(NG * NM),
                             dim3(256), args, 0, stream);
}

// Round 3
// 4342.071 us; speedup vs baseline: 2.6304x; 2.6304x over previous
//
#include <hip/hip_runtime.h>

typedef unsigned int u32;
typedef unsigned short u16;
typedef unsigned long long u64;
typedef float f32x4 __attribute__((ext_vector_type(4)));
typedef _Float16 f16x8 __attribute__((ext_vector_type(8)));

#define S_LEN 1024
#define NG 8      // groups (one per XCD, heuristically)
#define NM 32     // member blocks per group
#define GBAT 16   // batches per group

__device__ __forceinline__ u16 f2h_bits(float f) {
  _Float16 h = (_Float16)f;
  return __builtin_bit_cast(u16, h);
}
__device__ __forceinline__ float h2f_bits(u16 b) {
  return (float)__builtin_bit_cast(_Float16, b);
}
__device__ __forceinline__ u32 pk2(float a, float b) {
  return (u32)f2h_bits(a) | ((u32)f2h_bits(b) << 16);
}
// u64 = two h words (lo: k, hi: k+1), each (seq<<16 | f16). -> packed f16 pair
__device__ __forceinline__ u32 pkh(u64 v) {
  return (u32)(v & 0xFFFFu) | (((u32)(v >> 32) & 0xFFFFu) << 16);
}

// Pre-arrange W into MFMA fragment-major order, fp16 (same layout that passed r2).
// Per member m: frag[q(gate 0..3)][kc(0..15)][lane(0..63)] = uint4 (8 f16).
// Element (lane,e): k = kc*32 + (lane>>4)*8 + e ; gcol = q*512 + m*16 + (lane&15).
// Wi frags at wf4[0..131072), Wh frags at +131072 uint4.
__global__ __launch_bounds__(256) void prep_frags(const float* __restrict__ Wi,
                                                  const float* __restrict__ Wh,
                                                  uint4* __restrict__ wf4) {
  const int blk = blockIdx.x;               // 0..63
  const int m = blk & 31;
  const float* __restrict__ W = (blk & 32) ? Wh : Wi;
  uint4* __restrict__ dst = wf4 + ((blk & 32) ? 131072 : 0) + m * 4096;
  for (int fi = threadIdx.x; fi < 4096; fi += 256) {
    const int lane = fi & 63;
    const int kc = (fi >> 6) & 15;
    const int q = fi >> 10;
    const int gq = lane >> 4, c = lane & 15;
    const int kb = kc * 32 + gq * 8;
    const int gcol = q * 512 + m * 16 + c;
    u32 wds[4];
#pragma unroll
    for (int pp = 0; pp < 4; ++pp) {
      u16 e0 = f2h_bits(W[(size_t)(kb + 2 * pp) * 2048 + gcol]);
      u16 e1 = f2h_bits(W[(size_t)(kb + 2 * pp + 1) * 2048 + gcol]);
      wds[pp] = (u32)e0 | ((u32)e1 << 16);
    }
    uint4 v; v.x = wds[0]; v.y = wds[1]; v.z = wds[2]; v.w = wds[3];
    dst[fi] = v;    // fi == (q*16+kc)*64+lane
  }
}

// Persistent LSTM. Group g = bid&7 owns batches [g*16,g*16+16);
// member m = bid>>3 owns h-indices [m*16,m*16+16).
// hbuf[2][128][512] u32, word = (seq16 << 16) | f16(h). seq = step index t of h(t).
// Sync = spin on embedded tags; no barrier counter, no fences (LLC is the
// serialization point; agent-scope relaxed atomics bypass non-coherent L2).
__global__ __launch_bounds__(256) void lstm_main(
    const float* __restrict__ x,
    const uint4* __restrict__ wif4,
    u32* __restrict__ hbuf,
    const float* __restrict__ bvec,
    const float* __restrict__ Wd,
    const float* __restrict__ bd,
    float* __restrict__ out) {
  __shared__ __align__(16) uint4 sWi[4096];   // 64 KB
  __shared__ __align__(16) uint4 sWh[4096];   // 64 KB
  __shared__ float pred[16][256];             // 16 KB: [wv*4+q][row*16+col]

  const int tid = threadIdx.x;
  const int lane = tid & 63;
  const int wv = tid >> 6;
  const int g = blockIdx.x & 7;
  const int m = blockIdx.x >> 3;

  {  // weights -> LDS (once)
    for (int i = tid; i < 4096; i += 256) {
      sWi[i] = wif4[m * 4096 + i];
      sWh[i] = wif4[131072 + m * 4096 + i];
    }
  }

  const int bt = tid >> 4;          // batch within group (output row)
  const int hi_ = tid & 15;         // h-index within member slice (output col)
  const int gb = g * GBAT + bt;
  const int hidx = m * 16 + hi_;

  const float bi = bvec[hidx];
  const float bf_ = bvec[512 + hidx];
  const float bg = bvec[1024 + hidx];
  const float bo = bvec[1536 + hidx];
  float c_reg = 0.f;

  // per-lane A-fragment source coordinates
  const int abt = lane & 15;        // batch row this lane supplies
  const int oct = lane >> 4;        // k-octet within kc
  const float* __restrict__ xrow = x + (size_t)(g * GBAT + abt) * (S_LEN * 512);
  const u32 hrow_off = ((u32)(g * GBAT + abt)) << 9;   // u32 offset of batch row in a plane

  __syncthreads();   // LDS weights ready

  for (int t = 0; t < S_LEN; ++t) {
    f32x4 acc0 = {0.f, 0.f, 0.f, 0.f}, acc1 = acc0, acc2 = acc0, acc3 = acc0;

    // ---- x(t) @ Wi : independent of h; overlaps peers' publish propagation
#pragma unroll
    for (int kk = 0; kk < 4; ++kk) {
      const int kc = (wv << 2) | kk;
      const int k0 = kc * 32 + oct * 8;
      const float4* src = reinterpret_cast<const float4*>(xrow + (size_t)t * 512 + k0);
      float4 va = src[0], vb = src[1];
      uint4 av;
      av.x = pk2(va.x, va.y); av.y = pk2(va.z, va.w);
      av.z = pk2(vb.x, vb.y); av.w = pk2(vb.z, vb.w);
      f16x8 af = __builtin_bit_cast(f16x8, av);
      acc0 = __builtin_amdgcn_mfma_f32_16x16x32_f16(af, __builtin_bit_cast(f16x8, sWi[(0 * 16 + kc) * 64 + lane]), acc0, 0, 0, 0);
      acc1 = __builtin_amdgcn_mfma_f32_16x16x32_f16(af, __builtin_bit_cast(f16x8, sWi[(1 * 16 + kc) * 64 + lane]), acc1, 0, 0, 0);
      acc2 = __builtin_amdgcn_mfma_f32_16x16x32_f16(af, __builtin_bit_cast(f16x8, sWi[(2 * 16 + kc) * 64 + lane]), acc2, 0, 0, 0);
      acc3 = __builtin_amdgcn_mfma_f32_16x16x32_f16(af, __builtin_bit_cast(f16x8, sWi[(3 * 16 + kc) * 64 + lane]), acc3, 0, 0, 0);
    }

    // ---- h(t) @ Wh : poll-load h with embedded seq tags, then MFMA
    if (t > 0) {
      const u64* hp = reinterpret_cast<const u64*>(hbuf + (u32)(t & 1) * 65536u + hrow_off);
      const u32 want = (u32)t;
      const u64 wpat = ((u64)want << 16) | ((u64)want << 48);
      uint4 hv[4];
      for (;;) {
        u64 raw[4][4];
        u64 chk = 0;
#pragma unroll
        for (int kk = 0; kk < 4; ++kk) {
          const int base = (((wv << 2) | kk) << 4) | (oct << 2);  // u64 idx = k0/2
#pragma unroll
          for (int ee = 0; ee < 4; ++ee) {
            raw[kk][ee] = __hip_atomic_load(hp + base + ee, __ATOMIC_RELAXED,
                                            __HIP_MEMORY_SCOPE_AGENT);
            chk |= (raw[kk][ee] ^ wpat) & 0xFFFF0000FFFF0000ull;
          }
        }
        if (__all(chk == 0)) {
#pragma unroll
          for (int kk = 0; kk < 4; ++kk) {
            uint4 t4;
            t4.x = pkh(raw[kk][0]); t4.y = pkh(raw[kk][1]);
            t4.z = pkh(raw[kk][2]); t4.w = pkh(raw[kk][3]);
            hv[kk] = t4;
          }
          break;
        }
        __builtin_amdgcn_s_sleep(1);
      }
#pragma unroll
      for (int kk = 0; kk < 4; ++kk) {
        const int kc = (wv << 2) | kk;
        f16x8 hf = __builtin_bit_cast(f16x8, hv[kk]);
        acc0 = __builtin_amdgcn_mfma_f32_16x16x32_f16(hf, __builtin_bit_cast(f16x8, sWh[(0 * 16 + kc) * 64 + lane]), acc0, 0, 0, 0);
        acc1 = __builtin_amdgcn_mfma_f32_16x16x32_f16(hf, __builtin_bit_cast(f16x8, sWh[(1 * 16 + kc) * 64 + lane]), acc1, 0, 0, 0);
        acc2 = __builtin_amdgcn_mfma_f32_16x16x32_f16(hf, __builtin_bit_cast(f16x8, sWh[(2 * 16 + kc) * 64 + lane]), acc2, 0, 0, 0);
        acc3 = __builtin_amdgcn_mfma_f32_16x16x32_f16(hf, __builtin_bit_cast(f16x8, sWh[(3 * 16 + kc) * 64 + lane]), acc3, 0, 0, 0);
      }
    }

    // ---- K-partial tiles -> LDS (C/D layout as verified in r2)
    {
      const int r0 = (lane >> 4) << 2;
      const int cc = lane & 15;
#pragma unroll
      for (int r = 0; r < 4; ++r) {
        pred[wv * 4 + 0][(r0 + r) * 16 + cc] = acc0[r];
        pred[wv * 4 + 1][(r0 + r) * 16 + cc] = acc1[r];
        pred[wv * 4 + 2][(r0 + r) * 16 + cc] = acc2[r];
        pred[wv * 4 + 3][(r0 + r) * 16 + cc] = acc3[r];
      }
    }
    __syncthreads();

    // ---- gates; c in fp32 regs; publish h(t+1) with embedded tag
    {
      float gi = bi, gf = bf_, gg = bg, go = bo;
#pragma unroll
      for (int w2 = 0; w2 < 4; ++w2) {
        gi += pred[w2 * 4 + 0][tid];
        gf += pred[w2 * 4 + 1][tid];
        gg += pred[w2 * 4 + 2][tid];
        go += pred[w2 * 4 + 3][tid];
      }
      const float si = 1.f / (1.f + __expf(-gi));
      const float sf = 1.f / (1.f + __expf(-gf));
      const float so = 1.f / (1.f + __expf(-go));
      c_reg = sf * c_reg + si * tanhf(gg);
      const float hv_ = so * tanhf(c_reg);
      const u32 word = ((u32)(t + 1) << 16) | (u32)f2h_bits(hv_);
      __hip_atomic_store(hbuf + (u32)((t + 1) & 1) * 65536u + (u32)gb * 512u + (u32)hidx,
                         word, __ATOMIC_RELAXED, __HIP_MEMORY_SCOPE_AGENT);
    }
    // required: next step's pred writes vs this step's pred reads (poll ranges
    // don't cover own block, so the data-dependence argument doesn't apply intra-block)
    __syncthreads();
  }

  // ---- Dense(1) on h(S): member 0 of each group, spin on tags == S_LEN
  if (m == 0) {
    const int btf = tid >> 4;
    const int part = tid & 15;
    const u64* hp = reinterpret_cast<const u64*>(hbuf + (((u32)(g * GBAT + btf)) << 9)); // plane 0
    const u32 want = (u32)S_LEN;
    const u64 wpat = ((u64)want << 16) | ((u64)want << 48);
    float acc = 0.f;
    for (;;) {
      u64 rawv[16];
      u64 chk = 0;
#pragma unroll
      for (int j2 = 0; j2 < 16; ++j2) {
        rawv[j2] = __hip_atomic_load(hp + part * 16 + j2, __ATOMIC_RELAXED,
                                     __HIP_MEMORY_SCOPE_AGENT);
        chk |= (rawv[j2] ^ wpat) & 0xFFFF0000FFFF0000ull;
      }
      if (__all(chk == 0)) {
        acc = 0.f;
#pragma unroll
        for (int j2 = 0; j2 < 16; ++j2) {
          const int k = part * 32 + 2 * j2;
          acc += h2f_bits((u16)(rawv[j2] & 0xFFFFu)) * Wd[k] +
                 h2f_bits((u16)((rawv[j2] >> 32) & 0xFFFFu)) * Wd[k + 1];
        }
        break;
      }
      __builtin_amdgcn_s_sleep(1);
    }
#pragma unroll
    for (int s = 1; s < 16; s <<= 1) acc += __shfl_xor(acc, s, 64);
    if (part == 0) out[g * GBAT + btf] = acc + bd[0];
  }
}

extern "C" void kernel_launch(void* const* d_in, const int* in_sizes, int n_in,
                              void* d_out, int out_size, void* d_ws, size_t ws_size,
                              hipStream_t stream) {
  const float* x = (const float*)d_in[0];
  const float* Wi = (const float*)d_in[1];
  const float* Wh = (const float*)d_in[2];
  const float* bv = (const float*)d_in[3];
  const float* Wd = (const float*)d_in[4];
  const float* bd = (const float*)d_in[5];
  float* out = (float*)d_out;

  // ws layout: [0, 4MB) W frags | [4MB, 4.5MB) h ping-pong (tagged words)
  char* ws = (char*)d_ws;
  uint4* wif4 = (uint4*)ws;
  u32* hbuf = (u32*)(ws + (4u << 20));

  hipLaunchKernelGGL(prep_frags, dim3(64), dim3(256), 0, stream, Wi, Wh, wif4);

  const float* kx = x;
  const uint4* kw = wif4;
  u32* kh = hbuf;
  const float* kbv = bv;
  const float* kwd = Wd;
  const float* kbd = bd;
  float* ko = out;
  void* args[] = {&kx, &kw, &kh, &kbv, &kwd, &kbd, &ko};
  hipLaunchCooperativeKernel(reinterpret_cast<void*>(lstm_main), dim3(NG * NM),
                             dim3(256), args, 0, stream);
}